// Round 3
// baseline (4148.061 us; speedup 1.0000x reference)
//
#include <hip/hip_runtime.h>

#define V_   50000
#define OOV_ 100
#define VO_  50100
#define E_   128
#define HE_  256
#define HD_  256
#define B_   32
#define S_   256
#define T_   16
#define LG_  8   // LSTM blocks per batch

typedef _Float16 h2_t __attribute__((ext_vector_type(2)));
typedef __attribute__((ext_vector_type(8))) short bfrag_t;
typedef __attribute__((ext_vector_type(4))) float f32x4;
typedef unsigned short ushort_t;

union U32H2 { unsigned u; h2_t h; };
union FRAG  { uint4 u; bfrag_t s; };

static __device__ __forceinline__ float bf2f(unsigned short b) {
  return __uint_as_float(((unsigned)b) << 16);
}
static __device__ __forceinline__ unsigned short f2bf(float f) {
  unsigned u = __float_as_uint(f);
  unsigned r = (u + 0x7fffu + ((u >> 16) & 1u)) >> 16;
  return (unsigned short)r;
}
static __device__ __forceinline__ float sigm(float x) { return 1.f / (1.f + expf(-x)); }

static __device__ __forceinline__ float dot2u(unsigned upair, unsigned hpairv, float acc) {
  U32H2 a; a.u = upair;
  U32H2 b; b.u = hpairv;
#if __has_builtin(__builtin_amdgcn_fdot2)
  return __builtin_amdgcn_fdot2(a.h, b.h, acc, false);
#else
  acc = fmaf((float)a.h.x, (float)b.h.x, acc);
  return fmaf((float)a.h.y, (float)b.h.y, acc);
#endif
}

// ================= generic bf16 MFMA GEMM =================
// C[M,ldC] = act(A[M,K]@B[K,N] + bias); A row-major k-contig bf16; Bt = B^T [N][K] bf16.
// M mult of 64, K mult of 32, N guarded. act: 0 none, 1 tanh, 2 exp. Cbf!=null -> bf16 out.
__global__ __launch_bounds__(256) void mfma_gemm(
    const ushort_t* __restrict__ A, const ushort_t* __restrict__ Bt,
    const float* __restrict__ bias, float* __restrict__ C, ushort_t* __restrict__ Cbf,
    int M, int N, int K, int ldC, int act)
{
  const int w = threadIdx.x >> 6, lane = threadIdx.x & 63;
  const int m0 = blockIdx.y * 64 + w * 16;
  const int n0 = blockIdx.x * 64;
  const int l16 = lane & 15, lq = lane >> 4;
  f32x4 acc[4] = {f32x4{0,0,0,0}, f32x4{0,0,0,0}, f32x4{0,0,0,0}, f32x4{0,0,0,0}};
  for (int k0 = 0; k0 < K; k0 += 32) {
    FRAG a;
    a.u = *(const uint4*)(A + (size_t)(m0 + l16) * K + k0 + lq * 8);
#pragma unroll
    for (int ns = 0; ns < 4; ns++) {
      int n = n0 + ns * 16 + l16;
      int nc = n < N ? n : N - 1;
      FRAG bf;
      bf.u = *(const uint4*)(Bt + (size_t)nc * K + k0 + lq * 8);
      acc[ns] = __builtin_amdgcn_mfma_f32_16x16x32_bf16(a.s, bf.s, acc[ns], 0, 0, 0);
    }
  }
#pragma unroll
  for (int ns = 0; ns < 4; ns++) {
    int col = n0 + ns * 16 + l16;
    if (col < N) {
      float bv = bias ? bias[col] : 0.f;
#pragma unroll
      for (int r = 0; r < 4; r++) {
        int row = m0 + lq * 4 + r;   // C/D: col=lane&15, row=(lane>>4)*4+reg
        float v = acc[ns][r] + bv;
        if (act == 1) v = tanhf(v);
        else if (act == 2) v = expf(v);
        if (Cbf) Cbf[(size_t)row * ldC + col] = f2bf(v);
        else     C[(size_t)row * ldC + col] = v;
      }
    }
  }
}

// ================= transpose+convert: W fp32 [K][N] -> Wt bf16 [N][K] =================
__global__ __launch_bounds__(256) void tconv32(
    const float* __restrict__ W, ushort_t* __restrict__ Wt, int K, int N)
{
  __shared__ ushort_t tile[32][33];
  const int kb = blockIdx.y * 32, nb = blockIdx.x * 32;
  const int tx = threadIdx.x & 31, ty = threadIdx.x >> 5;
#pragma unroll
  for (int p = 0; p < 4; p++) {
    int k = kb + ty + p * 8, n = nb + tx;
    if (k < K && n < N) tile[ty + p * 8][tx] = f2bf(W[(size_t)k * N + n]);
  }
  __syncthreads();
#pragma unroll
  for (int p = 0; p < 4; p++) {
    int n = nb + ty + p * 8, k = kb + tx;
    if (k < K && n < N) Wt[(size_t)n * K + k] = tile[tx][ty + p * 8];
  }
}

// ================= LSTM v3: G=8 blocks/batch, U in VGPRs, global h-exchange =================
// Upk3: [g][t(256)][64] f16 k-pairs. Thread t: c=t&127 (gate=c>>5, jj=c&31), khalf=t>>7.
// hx: 2 slots x B*128 packed f16 h-pairs. ctr: per batch ctrW[steps+1], ctrR[steps+1].
__global__ __launch_bounds__(256) void lstm_rec3(
    const float* __restrict__ Xpre, const unsigned* __restrict__ Upk3,
    const float* __restrict__ h0, const float* __restrict__ c0,
    ushort_t* __restrict__ outH, float* __restrict__ hN, float* __restrict__ cN,
    unsigned* __restrict__ hx, unsigned* __restrict__ ctr, int steps)
{
  __shared__ unsigned hbuf[128];
  __shared__ float zred[128];
  __shared__ float zfull[128];
  const int tid = threadIdx.x;
  const int g = blockIdx.x, b = blockIdx.y;
  const int khalf = tid >> 7, c_ = tid & 127;

  uint4 Ur[16];
  const unsigned* ub = Upk3 + ((size_t)(g * 256 + tid)) * 64;
#pragma unroll
  for (int i = 0; i < 16; i++) Ur[i] = *(const uint4*)(ub + i * 4);

  unsigned* ctrW = ctr + (size_t)b * 2 * (steps + 1);
  unsigned* ctrR = ctrW + (steps + 1);

  const int j = g * 32 + (tid & 31);
  float cprev = 0.f, hcur = 0.f;
  if (tid < 32) {
    cprev = c0 ? c0[b * 256 + j] : 0.f;
    hcur  = h0 ? h0[b * 256 + j] : 0.f;
    float hnx = __shfl_down(hcur, 1);
    if ((tid & 1) == 0) {
      U32H2 cv; cv.h = h2_t{(_Float16)hcur, (_Float16)hnx};
      __hip_atomic_store(&hx[b * 128 + g * 16 + (tid >> 1)], cv.u,
                         __ATOMIC_RELAXED, __HIP_MEMORY_SCOPE_AGENT);
    }
    __threadfence();
  }
  __syncthreads();
  if (tid == 0)
    __hip_atomic_fetch_add(&ctrW[0], 1u, __ATOMIC_RELEASE, __HIP_MEMORY_SCOPE_AGENT);

  const float* xb = Xpre + (size_t)b * steps * 1024;

  for (int st = 0; st < steps; st++) {
    const int slot = st & 1, nslot = slot ^ 1;
    if (tid == 0) {
      while (__hip_atomic_load(&ctrW[st], __ATOMIC_RELAXED, __HIP_MEMORY_SCOPE_AGENT) < (unsigned)LG_)
        __builtin_amdgcn_s_sleep(1);
      __threadfence();
    }
    __syncthreads();
    if (tid < 128)
      hbuf[tid] = __hip_atomic_load(&hx[slot * (B_ * 128) + b * 128 + tid],
                                    __ATOMIC_RELAXED, __HIP_MEMORY_SCOPE_AGENT);
    __syncthreads();
    if (tid == 0)
      __hip_atomic_fetch_add(&ctrR[st], 1u, __ATOMIC_RELEASE, __HIP_MEMORY_SCOPE_AGENT);

    float xi = 0.f, xf = 0.f, xg = 0.f, xo = 0.f;
    if (tid < 32) {
      xi = xb[st * 1024 + j];
      xf = xb[st * 1024 + 256 + j];
      xg = xb[st * 1024 + 512 + j];
      xo = xb[st * 1024 + 768 + j];
    }
    float acc = 0.f;
#pragma unroll
    for (int i = 0; i < 16; i++) {
      uint4 h4 = *(const uint4*)&hbuf[khalf * 64 + i * 4];
      acc = dot2u(Ur[i].x, h4.x, acc);
      acc = dot2u(Ur[i].y, h4.y, acc);
      acc = dot2u(Ur[i].z, h4.z, acc);
      acc = dot2u(Ur[i].w, h4.w, acc);
    }
    if (khalf) zred[c_] = acc;
    __syncthreads();
    if (!khalf) zfull[c_] = acc + zred[c_];
    if (tid == 0 && st > 0) {  // write-safety: slot nslot was read by all at st-1
      while (__hip_atomic_load(&ctrR[st - 1], __ATOMIC_RELAXED, __HIP_MEMORY_SCOPE_AGENT) < (unsigned)LG_)
        __builtin_amdgcn_s_sleep(1);
    }
    __syncthreads();
    if (tid < 32) {
      float zi = xi + zfull[tid];
      float zf = xf + zfull[tid + 32];
      float zg = xg + zfull[tid + 64];
      float zo = xo + zfull[tid + 96];
      cprev = sigm(zf) * cprev + sigm(zi) * tanhf(zg);
      hcur = sigm(zo) * tanhf(cprev);
      outH[((size_t)b * steps + st) * 256 + j] = f2bf(hcur);
      float hnx = __shfl_down(hcur, 1);
      if ((tid & 1) == 0) {
        U32H2 cv; cv.h = h2_t{(_Float16)hcur, (_Float16)hnx};
        __hip_atomic_store(&hx[nslot * (B_ * 128) + b * 128 + g * 16 + (tid >> 1)], cv.u,
                           __ATOMIC_RELAXED, __HIP_MEMORY_SCOPE_AGENT);
      }
      __threadfence();
    }
    __syncthreads();
    if (tid == 0)
      __hip_atomic_fetch_add(&ctrW[st + 1], 1u, __ATOMIC_RELEASE, __HIP_MEMORY_SCOPE_AGENT);
  }
  if (tid < 32) {
    hN[b * 256 + j] = hcur;
    cN[b * 256 + j] = cprev;
  }
}

// U fp32 [256][1024] -> Upk3 [g][t][64] f16 k-pairs
__global__ __launch_bounds__(256) void packU3(const float* __restrict__ U, unsigned* __restrict__ out) {
  int i = blockIdx.x * 256 + threadIdx.x;   // 131072
  int i64 = i & 63, t = (i >> 6) & 255, g = i >> 14;
  int c = t & 127, khalf = t >> 7;
  int zcol = (c >> 5) * 256 + g * 32 + (c & 31);
  int k = khalf * 128 + 2 * i64;
  U32H2 cv; cv.h = h2_t{(_Float16)U[(size_t)k * 1024 + zcol], (_Float16)U[(size_t)(k + 1) * 1024 + zcol]};
  out[i] = cv.u;
}

// ================= attention: one block per (b,t), enc in bf16 =================
__global__ __launch_bounds__(256) void attn_kernel(
    const float* __restrict__ dq, const ushort_t* __restrict__ enc,
    const int* __restrict__ x_len, float* __restrict__ ctx)
{
  __shared__ float q[256];
  __shared__ float eb[32][256];
  __shared__ float sc[256];
  __shared__ float red[8];
  const int bt = blockIdx.x, tid = threadIdx.x;
  const int b = bt >> 4;
  q[tid] = dq[(size_t)bt * 256 + tid];
  const int len = x_len[b];
  const unsigned* encu = (const unsigned*)(enc + (size_t)b * S_ * 256);
  __syncthreads();
  const int s_loc = tid >> 3, hb = (tid & 7) * 32;
  for (int cch = 0; cch < 8; cch++) {
#pragma unroll
    for (int qv = 0; qv < 16; qv++) {
      int idx = qv * 256 + tid;        // 4096 uints = 32 rows x 128
      unsigned u = encu[cch * 4096 + idx];
      int row = idx >> 7, cp2 = (idx & 127) * 2;
      eb[row][cp2]     = bf2f((unsigned short)(u & 0xffffu));
      eb[row][cp2 + 1] = bf2f((unsigned short)(u >> 16));
    }
    __syncthreads();
    float p = 0.f;
#pragma unroll
    for (int h = 0; h < 32; h++) p = fmaf(q[hb + h], eb[s_loc][hb + h], p);
    p += __shfl_down(p, 4, 8);
    p += __shfl_down(p, 2, 8);
    p += __shfl_down(p, 1, 8);
    if ((tid & 7) == 0) sc[cch * 32 + s_loc] = p;
    __syncthreads();
  }
  float my = (tid < len) ? sc[tid] : -1e30f;
  float m = my;
#pragma unroll
  for (int o = 32; o >= 1; o >>= 1) m = fmaxf(m, __shfl_xor(m, o));
  if ((tid & 63) == 0) red[tid >> 6] = m;
  __syncthreads();
  float bm = fmaxf(fmaxf(red[0], red[1]), fmaxf(red[2], red[3]));
  float e = expf(my - bm);
  float s = e;
#pragma unroll
  for (int o = 32; o >= 1; o >>= 1) s += __shfl_xor(s, o);
  if ((tid & 63) == 0) red[4 + (tid >> 6)] = s;
  __syncthreads();
  float tot = red[4] + red[5] + red[6] + red[7];
  sc[tid] = e / tot;
  __syncthreads();
  const ushort_t* encb = enc + (size_t)b * S_ * 256;
  float acc = 0.f;
  for (int s2 = 0; s2 < 256; s2++) acc = fmaf(sc[s2], bf2f(encb[(size_t)s2 * 256 + tid]), acc);
  ctx[(size_t)bt * 256 + tid] = acc;
}

// ================= copy scores: one block per (b,t), cp in bf16 (tanh applied) =================
__global__ __launch_bounds__(256) void copyseq_kernel(
    const float* __restrict__ at, const ushort_t* __restrict__ cp,
    const int* __restrict__ x_len, float* __restrict__ cseq)
{
  __shared__ float q[256];
  __shared__ float eb[32][256];
  __shared__ float sc[256];
  const int bt = blockIdx.x, tid = threadIdx.x;
  const int b = bt >> 4;
  q[tid] = at[(size_t)bt * 256 + tid];
  const int len = x_len[b];
  const unsigned* cpu_ = (const unsigned*)(cp + (size_t)b * S_ * 256);
  __syncthreads();
  const int s_loc = tid >> 3, hb = (tid & 7) * 32;
  for (int cch = 0; cch < 8; cch++) {
#pragma unroll
    for (int qv = 0; qv < 16; qv++) {
      int idx = qv * 256 + tid;
      unsigned u = cpu_[cch * 4096 + idx];
      int row = idx >> 7, cp2 = (idx & 127) * 2;
      eb[row][cp2]     = bf2f((unsigned short)(u & 0xffffu));
      eb[row][cp2 + 1] = bf2f((unsigned short)(u >> 16));
    }
    __syncthreads();
    float p = 0.f;
#pragma unroll
    for (int h = 0; h < 32; h++) p = fmaf(q[hb + h], eb[s_loc][hb + h], p);
    p += __shfl_down(p, 4, 8);
    p += __shfl_down(p, 2, 8);
    p += __shfl_down(p, 1, 8);
    if ((tid & 7) == 0) sc[cch * 32 + s_loc] = p;
    __syncthreads();
  }
  cseq[(size_t)bt * 256 + tid] = (tid < len) ? expf(sc[tid]) : 0.f;
}

// ================= small kernels =================
__global__ void embed_bf(const int* __restrict__ idx, const float* __restrict__ emb,
                         ushort_t* __restrict__ out) {
  int r = blockIdx.x;
  out[(size_t)r * E_ + threadIdx.x] = f2bf(emb[(size_t)idx[r] * E_ + threadIdx.x]);
}
__global__ void f2bf_kernel(const float* __restrict__ in, ushort_t* __restrict__ out, int n) {
  int i = blockIdx.x * 256 + threadIdx.x;
  if (i < n) out[i] = f2bf(in[i]);
}
__global__ void concat_bf(const float* __restrict__ ctx, const ushort_t* __restrict__ dec,
                          ushort_t* __restrict__ cat) {
  int i = blockIdx.x * 256 + threadIdx.x;  // 512*512
  int r = i >> 9, j = i & 511;
  cat[i] = (j < 256) ? f2bf(ctx[r * 256 + j]) : dec[r * 256 + (j - 256)];
}
__global__ void pad_kernel(float* __restrict__ out) {
  int i = blockIdx.x * 256 + threadIdx.x;
  if (i < B_ * T_ * OOV_) {
    int bt = i / OOV_, j = i - bt * OOV_;
    out[(size_t)bt * VO_ + V_ + j] = 1e-10f;
  }
}
__global__ void scatter_kernel(const float* __restrict__ cseq, const int* __restrict__ xoov,
                               float* __restrict__ out) {
  int i = blockIdx.x * 256 + threadIdx.x;  // 131072
  int bt = i >> 8, s = i & 255, b = bt >> 4;
  float v = cseq[i];
  if (v != 0.f) atomicAdd(&out[(size_t)bt * VO_ + xoov[b * S_ + s]], v);
}
__global__ __launch_bounds__(256) void rowsum_kernel(const float* __restrict__ out,
                                                     float* __restrict__ rowlog) {
  __shared__ float red[256];
  int bt = blockIdx.x, tid = threadIdx.x;
  const float* row = out + (size_t)bt * VO_;
  float s = 0.f;
  for (int i = tid; i < VO_; i += 256) s += row[i];
  red[tid] = s;
  __syncthreads();
  for (int o = 128; o >= 1; o >>= 1) {
    if (tid < o) red[tid] += red[tid + o];
    __syncthreads();
  }
  if (tid == 0) rowlog[bt] = logf(red[0]);
}
__global__ void finalize_kernel(float* __restrict__ out, const float* __restrict__ rowlog) {
  size_t i = (size_t)blockIdx.x * 256 + threadIdx.x;
  if (i < (size_t)B_ * T_ * VO_) {
    int bt = (int)(i / VO_);
    out[i] = logf(out[i]) - rowlog[bt];
  }
}

extern "C" void kernel_launch(void* const* d_in, const int* in_sizes, int n_in,
                              void* d_out, int out_size, void* d_ws, size_t ws_size,
                              hipStream_t stream) {
  const int*   x     = (const int*)d_in[0];
  const int*   xoov  = (const int*)d_in[1];
  const int*   xlen  = (const int*)d_in[2];
  const int*   decx  = (const int*)d_in[3];
  const float* emb   = (const float*)d_in[4];
  const float* Wenc  = (const float*)d_in[5];
  const float* Uenc  = (const float*)d_in[6];
  const float* benc  = (const float*)d_in[7];
  const float* We2d  = (const float*)d_in[8];
  const float* be2d  = (const float*)d_in[9];
  const float* Wdec  = (const float*)d_in[10];
  const float* Udec  = (const float*)d_in[11];
  const float* bdec  = (const float*)d_in[12];
  const float* Wattn = (const float*)d_in[13];
  const float* Wout  = (const float*)d_in[14];
  const float* bout  = (const float*)d_in[15];
  const float* Wgen  = (const float*)d_in[16];
  const float* Wcopy = (const float*)d_in[17];
  const float* bcopy = (const float*)d_in[18];
  float* out = (float*)d_out;
  float* ws  = (float*)d_ws;

  // ---- workspace layout (float offsets), total 48.8 MB ----
  float*    Xenc   = ws + 0;                               // 8,388,608 fl (phase 1)
  ushort_t* WgenT  = (ushort_t*)(ws + 0);                  // phase 2: 12.8M ush
  ushort_t* cp_bf  = (ushort_t*)(ws + 6400000);            // phase 2: 2.1M ush
  float*    dqb    = ws + 8388608;
  float*    ctxb   = ws + 8519680;
  float*    attno  = ws + 8650752;
  float*    cseq   = ws + 8781824;
  float*    rowlog = ws + 8912896;
  ushort_t* Abf    = (ushort_t*)(ws + 8913408);
  ushort_t* catb   = (ushort_t*)(ws + 8978944);
  ushort_t* decObf = (ushort_t*)(ws + 9110016);
  ushort_t* xembbf = (ushort_t*)(ws + 9437184);
  ushort_t* dembbf = (ushort_t*)(ws + 9961472);
  float*    Xdec   = ws + 9994240;
  ushort_t* WencT  = (ushort_t*)(ws + 10518528);
  ushort_t* WdecT  = (ushort_t*)(ws + 10584064);
  ushort_t* We2dT  = (ushort_t*)(ws + 10649600);
  ushort_t* WattnT = (ushort_t*)(ws + 10682368);
  ushort_t* WoutT  = (ushort_t*)(ws + 10715136);
  ushort_t* WcopyT = (ushort_t*)(ws + 10780672);
  unsigned* Upk3E  = (unsigned*)(ws + 10813440);
  unsigned* Upk3D  = (unsigned*)(ws + 10944512);
  ushort_t* encObf = (ushort_t*)(ws + 11075584);
  float*    ehc    = ws + 12124160;
  ushort_t* ehcbf  = (ushort_t*)(ws + 12140544);
  float*    h0c0   = ws + 12148736;
  unsigned* hxE    = (unsigned*)(ws + 12165120);
  unsigned* hxD    = (unsigned*)(ws + 12173312);
  unsigned* ctrE   = (unsigned*)(ws + 12181504);           // 16,448 uints
  unsigned* ctrD   = (unsigned*)(ws + 12197952);           // 1,088 uints

  float* sh  = out + (size_t)B_ * T_ * VO_;
  float* scf = sh + B_ * HD_;

  hipMemsetAsync(ctrE, 0, (16448 + 1088) * sizeof(unsigned), stream);

  hipLaunchKernelGGL(tconv32, dim3(32, 4), dim3(256), 0, stream, Wenc, WencT, 128, 1024);
  hipLaunchKernelGGL(tconv32, dim3(32, 4), dim3(256), 0, stream, Wdec, WdecT, 128, 1024);
  hipLaunchKernelGGL(tconv32, dim3(8, 8), dim3(256), 0, stream, We2d, We2dT, 256, 256);
  hipLaunchKernelGGL(tconv32, dim3(8, 8), dim3(256), 0, stream, Wattn, WattnT, 256, 256);
  hipLaunchKernelGGL(tconv32, dim3(8, 16), dim3(256), 0, stream, Wout, WoutT, 512, 256);
  hipLaunchKernelGGL(tconv32, dim3(8, 8), dim3(256), 0, stream, Wcopy, WcopyT, 256, 256);
  hipLaunchKernelGGL(packU3, dim3(512), dim3(256), 0, stream, Uenc, Upk3E);
  hipLaunchKernelGGL(packU3, dim3(512), dim3(256), 0, stream, Udec, Upk3D);
  hipLaunchKernelGGL(embed_bf, dim3(B_ * S_), dim3(E_), 0, stream, x, emb, xembbf);
  hipLaunchKernelGGL(embed_bf, dim3(B_ * T_), dim3(E_), 0, stream, decx, emb, dembbf);

  hipLaunchKernelGGL(mfma_gemm, dim3(16, 128), dim3(256), 0, stream,
                     xembbf, WencT, benc, Xenc, (ushort_t*)nullptr, B_ * S_, 1024, 128, 1024, 0);
  hipLaunchKernelGGL(mfma_gemm, dim3(16, 8), dim3(256), 0, stream,
                     dembbf, WdecT, bdec, Xdec, (ushort_t*)nullptr, B_ * T_, 1024, 128, 1024, 0);

  hipLaunchKernelGGL(lstm_rec3, dim3(LG_, B_), dim3(256), 0, stream,
                     Xenc, Upk3E, (const float*)nullptr, (const float*)nullptr,
                     encObf, ehc, ehc + 32 * 256, hxE, ctrE, S_);

  hipLaunchKernelGGL(f2bf_kernel, dim3(64), dim3(256), 0, stream, ehc, ehcbf, 64 * 256);
  hipLaunchKernelGGL(mfma_gemm, dim3(4, 1), dim3(256), 0, stream,
                     ehcbf, We2dT, be2d, h0c0, (ushort_t*)nullptr, 64, 256, 256, 256, 0);

  hipLaunchKernelGGL(tconv32, dim3(1563, 8), dim3(256), 0, stream, Wgen, WgenT, 256, V_);

  hipLaunchKernelGGL(lstm_rec3, dim3(LG_, B_), dim3(256), 0, stream,
                     Xdec, Upk3D, h0c0, h0c0 + 32 * 256, decObf, sh, scf, hxD, ctrD, T_);

  hipLaunchKernelGGL(mfma_gemm, dim3(4, 8), dim3(256), 0, stream,
                     decObf, WattnT, (const float*)nullptr, dqb, (ushort_t*)nullptr,
                     B_ * T_, 256, 256, 256, 0);
  hipLaunchKernelGGL(attn_kernel, dim3(B_ * T_), dim3(256), 0, stream, dqb, encObf, xlen, ctxb);
  hipLaunchKernelGGL(concat_bf, dim3(1024), dim3(256), 0, stream, ctxb, decObf, catb);
  hipLaunchKernelGGL(mfma_gemm, dim3(4, 8), dim3(256), 0, stream,
                     catb, WoutT, bout, attno, (ushort_t*)nullptr, B_ * T_, 256, 512, 256, 1);
  hipLaunchKernelGGL(f2bf_kernel, dim3(512), dim3(256), 0, stream, attno, Abf, B_ * T_ * 256);
  hipLaunchKernelGGL(mfma_gemm, dim3(4, 128), dim3(256), 0, stream,
                     encObf, WcopyT, bcopy, (float*)nullptr, cp_bf, B_ * S_, 256, 256, 256, 1);
  hipLaunchKernelGGL(mfma_gemm, dim3(782, 8), dim3(256), 0, stream,
                     Abf, WgenT, (const float*)nullptr, out, (ushort_t*)nullptr,
                     B_ * T_, V_, 256, VO_, 2);
  hipLaunchKernelGGL(pad_kernel, dim3(200), dim3(256), 0, stream, out);
  hipLaunchKernelGGL(copyseq_kernel, dim3(B_ * T_), dim3(256), 0, stream, attno, cp_bf, xlen, cseq);
  hipLaunchKernelGGL(scatter_kernel, dim3(512), dim3(256), 0, stream, cseq, xoov, out);
  hipLaunchKernelGGL(rowsum_kernel, dim3(B_ * T_), dim3(256), 0, stream, out, rowlog);
  hipLaunchKernelGGL(finalize_kernel, dim3((B_ * T_ * VO_ + 255) / 256), dim3(256), 0, stream,
                     out, rowlog);
}

// Round 4
// 1200.310 us; speedup vs baseline: 3.4558x; 3.4558x over previous
//
#include <hip/hip_runtime.h>

#define V_   50000
#define OOV_ 100
#define VO_  50100
#define E_   128
#define HE_  256
#define HD_  256
#define B_   32
#define S_   256
#define T_   16

typedef _Float16 h2_t __attribute__((ext_vector_type(2)));
typedef __attribute__((ext_vector_type(8))) short bfrag_t;
typedef __attribute__((ext_vector_type(4))) float f32x4;
typedef unsigned short ushort_t;

union U32H2 { unsigned u; h2_t h; };
union FRAG  { uint4 u; bfrag_t s; };

static __device__ __forceinline__ float bf2f(unsigned short b) {
  return __uint_as_float(((unsigned)b) << 16);
}
static __device__ __forceinline__ unsigned short f2bf(float f) {
  unsigned u = __float_as_uint(f);
  unsigned r = (u + 0x7fffu + ((u >> 16) & 1u)) >> 16;
  return (unsigned short)r;
}
static __device__ __forceinline__ float sigm(float x) { return 1.f / (1.f + expf(-x)); }

static __device__ __forceinline__ float dot2u(unsigned upair, unsigned hpairv, float acc) {
  U32H2 a; a.u = upair;
  U32H2 b; b.u = hpairv;
#if __has_builtin(__builtin_amdgcn_fdot2)
  return __builtin_amdgcn_fdot2(a.h, b.h, acc, false);
#else
  acc = fmaf((float)a.h.x, (float)b.h.x, acc);
  return fmaf((float)a.h.y, (float)b.h.y, acc);
#endif
}

// ================= generic bf16 MFMA GEMM (+optional fused row-sum) =================
// C[M,ldC] = act(A[M,K]@Bt^T + bias); A row-major k-contig bf16; Bt [N][K] bf16.
// act: 0 none, 1 tanh, 2 exp. Cbf!=null -> bf16 out. rsum!=null -> atomicAdd row sums.
__global__ __launch_bounds__(256) void mfma_gemm(
    const ushort_t* __restrict__ A, const ushort_t* __restrict__ Bt,
    const float* __restrict__ bias, float* __restrict__ C, ushort_t* __restrict__ Cbf,
    float* __restrict__ rsum, int M, int N, int K, int ldC, int act)
{
  const int w = threadIdx.x >> 6, lane = threadIdx.x & 63;
  const int m0 = blockIdx.y * 64 + w * 16;
  const int n0 = blockIdx.x * 64;
  const int l16 = lane & 15, lq = lane >> 4;
  f32x4 acc[4] = {f32x4{0,0,0,0}, f32x4{0,0,0,0}, f32x4{0,0,0,0}, f32x4{0,0,0,0}};
  for (int k0 = 0; k0 < K; k0 += 32) {
    FRAG a;
    a.u = *(const uint4*)(A + (size_t)(m0 + l16) * K + k0 + lq * 8);
#pragma unroll
    for (int ns = 0; ns < 4; ns++) {
      int n = n0 + ns * 16 + l16;
      int nc = n < N ? n : N - 1;
      FRAG bf;
      bf.u = *(const uint4*)(Bt + (size_t)nc * K + k0 + lq * 8);
      acc[ns] = __builtin_amdgcn_mfma_f32_16x16x32_bf16(a.s, bf.s, acc[ns], 0, 0, 0);
    }
  }
  float bv[4];
#pragma unroll
  for (int ns = 0; ns < 4; ns++) {
    int col = n0 + ns * 16 + l16;
    bv[ns] = (bias && col < N) ? bias[col] : 0.f;
  }
#pragma unroll
  for (int r = 0; r < 4; r++) {
    int row = m0 + lq * 4 + r;   // C/D: col=lane&15, row=(lane>>4)*4+reg
    float part = 0.f;
#pragma unroll
    for (int ns = 0; ns < 4; ns++) {
      int col = n0 + ns * 16 + l16;
      if (col < N) {
        float v = acc[ns][r] + bv[ns];
        if (act == 1) v = tanhf(v);
        else if (act == 2) v = expf(v);
        if (Cbf) Cbf[(size_t)row * ldC + col] = f2bf(v);
        else     C[(size_t)row * ldC + col] = v;
        part += v;
      }
    }
    if (rsum) {
      part += __shfl_xor(part, 1);
      part += __shfl_xor(part, 2);
      part += __shfl_xor(part, 4);
      part += __shfl_xor(part, 8);
      if (l16 == 0) atomicAdd(&rsum[row], part);
    }
  }
}

// ================= prep: all weight transposes / packs / embeds, role-dispatched ==========
static __device__ __forceinline__ void tconv_tile(
    const float* __restrict__ W, ushort_t* __restrict__ Wt, int K, int N,
    int kb, int nb, int tid, ushort_t (*tile)[33])
{
  const int tx = tid & 31, ty = tid >> 5;
#pragma unroll
  for (int p = 0; p < 4; p++) {
    int k = kb + ty + p * 8, n = nb + tx;
    if (k < K && n < N) tile[ty + p * 8][tx] = f2bf(W[(size_t)k * N + n]);
  }
  __syncthreads();
#pragma unroll
  for (int p = 0; p < 4; p++) {
    int n = nb + ty + p * 8, k = kb + tx;
    if (k < K && n < N) Wt[(size_t)n * K + k] = tile[tx][ty + p * 8];
  }
}
static __device__ __forceinline__ void packU2_one(
    const float* __restrict__ U, unsigned* __restrict__ out, int i)
{
  int p = i >> 10, col = i & 1023;
  U32H2 cv; cv.h = h2_t{(_Float16)U[(size_t)(2 * p) * 1024 + col],
                        (_Float16)U[(size_t)(2 * p + 1) * 1024 + col]};
  out[i] = cv.u;
}

__global__ __launch_bounds__(256) void prep_kernel(
    const float* __restrict__ Wenc, const float* __restrict__ Wdec,
    const float* __restrict__ We2d, const float* __restrict__ Wattn,
    const float* __restrict__ Wout, const float* __restrict__ Wcopy,
    const float* __restrict__ Uenc, const float* __restrict__ Udec,
    const int* __restrict__ x, const int* __restrict__ decx, const float* __restrict__ emb,
    ushort_t* WencT, ushort_t* WdecT, ushort_t* We2dT, ushort_t* WattnT,
    ushort_t* WoutT, ushort_t* WcopyT, unsigned* Upk2E, unsigned* Upk2D,
    ushort_t* xembbf, ushort_t* dembbf)
{
  __shared__ ushort_t tile[32][33];
  int blk = blockIdx.x;
  const int tid = threadIdx.x;
  if (blk < 128) { tconv_tile(Wenc, WencT, 128, 1024, (blk >> 5) * 32, (blk & 31) * 32, tid, tile); return; }
  blk -= 128;
  if (blk < 128) { tconv_tile(Wdec, WdecT, 128, 1024, (blk >> 5) * 32, (blk & 31) * 32, tid, tile); return; }
  blk -= 128;
  if (blk < 64)  { tconv_tile(We2d, We2dT, 256, 256, (blk >> 3) * 32, (blk & 7) * 32, tid, tile); return; }
  blk -= 64;
  if (blk < 64)  { tconv_tile(Wattn, WattnT, 256, 256, (blk >> 3) * 32, (blk & 7) * 32, tid, tile); return; }
  blk -= 64;
  if (blk < 128) { tconv_tile(Wout, WoutT, 512, 256, (blk >> 3) * 32, (blk & 7) * 32, tid, tile); return; }
  blk -= 128;
  if (blk < 64)  { tconv_tile(Wcopy, WcopyT, 256, 256, (blk >> 3) * 32, (blk & 7) * 32, tid, tile); return; }
  blk -= 64;
  if (blk < 512) { packU2_one(Uenc, Upk2E, blk * 256 + tid); return; }
  blk -= 512;
  if (blk < 512) { packU2_one(Udec, Upk2D, blk * 256 + tid); return; }
  blk -= 512;
  if (blk < 4096) {
    int i = blk * 256 + tid, r = i >> 7;
    xembbf[i] = f2bf(emb[(size_t)x[r] * E_ + (i & 127)]);
    return;
  }
  blk -= 4096;
  {
    int i = blk * 256 + tid, r = i >> 7;
    dembbf[i] = f2bf(emb[(size_t)decx[r] * E_ + (i & 127)]);
  }
}

// ================= LSTM v4: 1 block/batch, 1024 thr, U resident; optional fused transpose ==
// Upk2: [128 k-pairs][1024 cols] packed f16 pairs. thread (jg=tid>>3, kq=tid&7):
// cols jg*8..+8, k in [kq*32, kq*32+32). Blocks >=32 (decoder dispatch): Wgen transpose.
#define DOT8(u0, u1, hpi)                \
  acc[0] = dot2u(u0.x, hpi, acc[0]);     \
  acc[1] = dot2u(u0.y, hpi, acc[1]);     \
  acc[2] = dot2u(u0.z, hpi, acc[2]);     \
  acc[3] = dot2u(u0.w, hpi, acc[3]);     \
  acc[4] = dot2u(u1.x, hpi, acc[4]);     \
  acc[5] = dot2u(u1.y, hpi, acc[5]);     \
  acc[6] = dot2u(u1.z, hpi, acc[6]);     \
  acc[7] = dot2u(u1.w, hpi, acc[7]);

__global__ __launch_bounds__(1024, 4) void lstm4(
    const float* __restrict__ Xpre, const unsigned* __restrict__ Upk2,
    const float* __restrict__ h0, const float* __restrict__ c0,
    ushort_t* __restrict__ outH, float* __restrict__ hN, float* __restrict__ cN,
    int steps, const float* __restrict__ Wg, ushort_t* __restrict__ WgT)
{
  __shared__ unsigned ldsU[32 * 1028];   // 131.6 KB
  __shared__ float zpart[4 * 1028];      // 16.4 KB
  __shared__ float actbuf[1024];         // 4 KB
  __shared__ unsigned hpair[128];        // 0.5 KB
  const int tid = threadIdx.x;

  if (blockIdx.x >= 32) {
    // --- Wgen transpose role (runs on idle CUs during decoder) ---
    ushort_t* tile = (ushort_t*)ldsU;    // [64][65]
    int tb = blockIdx.x - 32;            // 3128 tiles: 4 k-tiles x 782 n-tiles
    int kb = (tb & 3) * 64, nb = (tb >> 2) * 64;
#pragma unroll
    for (int p = 0; p < 4; p++) {
      int i = p * 1024 + tid, k = i >> 6, n = i & 63;
      if (nb + n < V_) tile[k * 65 + n] = f2bf(Wg[(size_t)(kb + k) * V_ + nb + n]);
    }
    __syncthreads();
#pragma unroll
    for (int p = 0; p < 4; p++) {
      int i = p * 1024 + tid, n = i >> 6, k = i & 63;
      if (nb + n < V_) WgT[(size_t)(nb + n) * 256 + kb + k] = tile[k * 65 + n];
    }
    return;
  }

  const int b = blockIdx.x;
  const int jg = tid >> 3, kq = tid & 7;

  // load U: 12 pair-rows to regs, 4 to LDS
  uint4 Ur[24];
  const unsigned* ubase = Upk2 + jg * 8;
#pragma unroll
  for (int i = 0; i < 12; i++) {
    int p = kq * 16 + i;
    Ur[2 * i]     = *(const uint4*)(ubase + p * 1024);
    Ur[2 * i + 1] = *(const uint4*)(ubase + p * 1024 + 4);
  }
#pragma unroll
  for (int i = 0; i < 4; i++) {
    int p = kq * 16 + 12 + i;
    uint4 q0 = *(const uint4*)(ubase + p * 1024);
    uint4 q1 = *(const uint4*)(ubase + p * 1024 + 4);
    *(uint4*)&ldsU[(kq * 4 + i) * 1028 + jg * 8] = q0;
    *(uint4*)&ldsU[(kq * 4 + i) * 1028 + jg * 8 + 4] = q1;
  }
  float c = 0.f, hcur = 0.f;
  if (tid < 256) {
    c    = c0 ? c0[b * 256 + tid] : 0.f;
    hcur = h0 ? h0[b * 256 + tid] : 0.f;
  }
  if (tid < 128) {
    float a  = h0 ? h0[b * 256 + 2 * tid] : 0.f;
    float b2 = h0 ? h0[b * 256 + 2 * tid + 1] : 0.f;
    U32H2 cv; cv.h = h2_t{(_Float16)a, (_Float16)b2};
    hpair[tid] = cv.u;
  }
  __syncthreads();

  const float* xp = Xpre + (size_t)b * steps * 1024;
  const unsigned* myld = &ldsU[kq * 4 * 1028 + jg * 8];

  for (int t = 0; t < steps; t++) {
    float xv = xp[t * 1024 + tid];       // all 1024 threads: own z-column's x
    float acc[8] = {0.f, 0.f, 0.f, 0.f, 0.f, 0.f, 0.f, 0.f};
    {
      uint4 hA = *(const uint4*)&hpair[kq * 16];
      DOT8(Ur[0], Ur[1], hA.x)  DOT8(Ur[2], Ur[3], hA.y)
      DOT8(Ur[4], Ur[5], hA.z)  DOT8(Ur[6], Ur[7], hA.w)
    }
    {
      uint4 hB = *(const uint4*)&hpair[kq * 16 + 4];
      DOT8(Ur[8], Ur[9], hB.x)   DOT8(Ur[10], Ur[11], hB.y)
      DOT8(Ur[12], Ur[13], hB.z) DOT8(Ur[14], Ur[15], hB.w)
    }
    {
      uint4 hC = *(const uint4*)&hpair[kq * 16 + 8];
      DOT8(Ur[16], Ur[17], hC.x) DOT8(Ur[18], Ur[19], hC.y)
      DOT8(Ur[20], Ur[21], hC.z) DOT8(Ur[22], Ur[23], hC.w)
    }
    {
      uint4 hD = *(const uint4*)&hpair[kq * 16 + 12];
      unsigned hh[4] = {hD.x, hD.y, hD.z, hD.w};
#pragma unroll
      for (int r = 0; r < 4; r++) {
        uint4 u0 = *(const uint4*)(myld + r * 1028);
        uint4 u1 = *(const uint4*)(myld + r * 1028 + 4);
        unsigned hpi = hh[r];
        DOT8(u0, u1, hpi)
      }
    }
#pragma unroll
    for (int g = 0; g < 8; g++) acc[g] += __shfl_xor(acc[g], 1);
    if ((kq & 1) == 0) {
      int r = kq >> 1;
      *(float4*)&zpart[r * 1028 + jg * 8]     = make_float4(acc[0], acc[1], acc[2], acc[3]);
      *(float4*)&zpart[r * 1028 + jg * 8 + 4] = make_float4(acc[4], acc[5], acc[6], acc[7]);
    }
    __syncthreads();
    // all 1024 threads: finish own z column + activation
    float z = xv + zpart[tid] + zpart[1028 + tid] + zpart[2 * 1028 + tid] + zpart[3 * 1028 + tid];
    actbuf[tid] = (tid >= 512 && tid < 768) ? tanhf(z) : sigm(z);
    __syncthreads();
    if (tid < 256) {
      float ai = actbuf[tid], af = actbuf[tid + 256];
      float gg = actbuf[tid + 512], ao = actbuf[tid + 768];
      c = af * c + ai * gg;
      hcur = ao * tanhf(c);
      outH[((size_t)b * steps + t) * 256 + tid] = f2bf(hcur);
      float hnx = __shfl_down(hcur, 1);
      if ((tid & 1) == 0) {
        U32H2 cv; cv.h = h2_t{(_Float16)hcur, (_Float16)hnx};
        hpair[tid >> 1] = cv.u;
      }
    }
    __syncthreads();
  }
  if (tid < 256) {
    hN[b * 256 + tid] = hcur;
    cN[b * 256 + tid] = c;
  }
}

// ================= attention: one block per (b,t), enc in bf16 =================
__global__ __launch_bounds__(256) void attn_kernel(
    const float* __restrict__ dq, const ushort_t* __restrict__ enc,
    const int* __restrict__ x_len, float* __restrict__ ctx)
{
  __shared__ float q[256];
  __shared__ float eb[32][256];
  __shared__ float sc[256];
  __shared__ float red[8];
  const int bt = blockIdx.x, tid = threadIdx.x;
  const int b = bt >> 4;
  q[tid] = dq[(size_t)bt * 256 + tid];
  const int len = x_len[b];
  const unsigned* encu = (const unsigned*)(enc + (size_t)b * S_ * 256);
  __syncthreads();
  const int s_loc = tid >> 3, hb = (tid & 7) * 32;
  for (int cch = 0; cch < 8; cch++) {
#pragma unroll
    for (int qv = 0; qv < 16; qv++) {
      int idx = qv * 256 + tid;
      unsigned u = encu[cch * 4096 + idx];
      int row = idx >> 7, cp2 = (idx & 127) * 2;
      eb[row][cp2]     = bf2f((unsigned short)(u & 0xffffu));
      eb[row][cp2 + 1] = bf2f((unsigned short)(u >> 16));
    }
    __syncthreads();
    float p = 0.f;
#pragma unroll
    for (int h = 0; h < 32; h++) p = fmaf(q[hb + h], eb[s_loc][hb + h], p);
    p += __shfl_down(p, 4, 8);
    p += __shfl_down(p, 2, 8);
    p += __shfl_down(p, 1, 8);
    if ((tid & 7) == 0) sc[cch * 32 + s_loc] = p;
    __syncthreads();
  }
  float my = (tid < len) ? sc[tid] : -1e30f;
  float m = my;
#pragma unroll
  for (int o = 32; o >= 1; o >>= 1) m = fmaxf(m, __shfl_xor(m, o));
  if ((tid & 63) == 0) red[tid >> 6] = m;
  __syncthreads();
  float bm = fmaxf(fmaxf(red[0], red[1]), fmaxf(red[2], red[3]));
  float e = expf(my - bm);
  float s = e;
#pragma unroll
  for (int o = 32; o >= 1; o >>= 1) s += __shfl_xor(s, o);
  if ((tid & 63) == 0) red[4 + (tid >> 6)] = s;
  __syncthreads();
  float tot = red[4] + red[5] + red[6] + red[7];
  sc[tid] = e / tot;
  __syncthreads();
  const ushort_t* encb = enc + (size_t)b * S_ * 256;
  float acc = 0.f;
  for (int s2 = 0; s2 < 256; s2++) acc = fmaf(sc[s2], bf2f(encb[(size_t)s2 * 256 + tid]), acc);
  ctx[(size_t)bt * 256 + tid] = acc;
}

// ================= copy scores: one block per (b,t), cp in bf16 (tanh applied) ============
__global__ __launch_bounds__(256) void copyseq_kernel(
    const float* __restrict__ at, const ushort_t* __restrict__ cp,
    const int* __restrict__ x_len, float* __restrict__ cseq)
{
  __shared__ float q[256];
  __shared__ float eb[32][256];
  __shared__ float sc[256];
  const int bt = blockIdx.x, tid = threadIdx.x;
  const int b = bt >> 4;
  q[tid] = at[(size_t)bt * 256 + tid];
  const int len = x_len[b];
  const unsigned* cpu_ = (const unsigned*)(cp + (size_t)b * S_ * 256);
  __syncthreads();
  const int s_loc = tid >> 3, hb = (tid & 7) * 32;
  for (int cch = 0; cch < 8; cch++) {
#pragma unroll
    for (int qv = 0; qv < 16; qv++) {
      int idx = qv * 256 + tid;
      unsigned u = cpu_[cch * 4096 + idx];
      int row = idx >> 7, cp2 = (idx & 127) * 2;
      eb[row][cp2]     = bf2f((unsigned short)(u & 0xffffu));
      eb[row][cp2 + 1] = bf2f((unsigned short)(u >> 16));
    }
    __syncthreads();
    float p = 0.f;
#pragma unroll
    for (int h = 0; h < 32; h++) p = fmaf(q[hb + h], eb[s_loc][hb + h], p);
    p += __shfl_down(p, 4, 8);
    p += __shfl_down(p, 2, 8);
    p += __shfl_down(p, 1, 8);
    if ((tid & 7) == 0) sc[cch * 32 + s_loc] = p;
    __syncthreads();
  }
  cseq[(size_t)bt * 256 + tid] = (tid < len) ? expf(sc[tid]) : 0.f;
}

// ================= small kernels =================
__global__ void f2bf_kernel(const float* __restrict__ in, ushort_t* __restrict__ out, int n) {
  int i = blockIdx.x * 256 + threadIdx.x;
  if (i < n) out[i] = f2bf(in[i]);
}
__global__ void concat_bf(const float* __restrict__ ctx, const ushort_t* __restrict__ dec,
                          ushort_t* __restrict__ cat) {
  int i = blockIdx.x * 256 + threadIdx.x;  // 512*512
  int r = i >> 9, j = i & 511;
  cat[i] = (j < 256) ? f2bf(ctx[r * 256 + j]) : dec[r * 256 + (j - 256)];
}
__global__ void pad_kernel(float* __restrict__ out) {
  int i = blockIdx.x * 256 + threadIdx.x;
  if (i < B_ * T_ * OOV_) {
    int bt = i / OOV_, j = i - bt * OOV_;
    out[(size_t)bt * VO_ + V_ + j] = 1e-10f;
  }
}
// one block per bt-row; adds block's cseq sum to rsum
__global__ __launch_bounds__(256) void scatter_kernel(
    const float* __restrict__ cseq, const int* __restrict__ xoov,
    float* __restrict__ out, float* __restrict__ rsum)
{
  __shared__ float red[4];
  const int bt = blockIdx.x, tid = threadIdx.x, b = bt >> 4;
  float v = cseq[(size_t)bt * 256 + tid];
  if (v != 0.f) atomicAdd(&out[(size_t)bt * VO_ + xoov[b * S_ + tid]], v);
  float s = v;
#pragma unroll
  for (int o = 32; o >= 1; o >>= 1) s += __shfl_xor(s, o);
  if ((tid & 63) == 0) red[tid >> 6] = s;
  __syncthreads();
  if (tid == 0) atomicAdd(&rsum[bt], red[0] + red[1] + red[2] + red[3]);
}
__global__ void rowlog_kernel(const float* __restrict__ rsum, float* __restrict__ rowlog) {
  int i = blockIdx.x * 256 + threadIdx.x;
  if (i < B_ * T_) rowlog[i] = logf(rsum[i] + 1e-8f);  // +1e-8 = 100 pad cells * 1e-10
}
__global__ void finalize_kernel(float* __restrict__ out, const float* __restrict__ rowlog) {
  size_t i = (size_t)blockIdx.x * 256 + threadIdx.x;
  if (i < (size_t)B_ * T_ * VO_) {
    int bt = (int)(i / VO_);
    out[i] = logf(out[i]) - rowlog[bt];
  }
}

extern "C" void kernel_launch(void* const* d_in, const int* in_sizes, int n_in,
                              void* d_out, int out_size, void* d_ws, size_t ws_size,
                              hipStream_t stream) {
  const int*   x     = (const int*)d_in[0];
  const int*   xoov  = (const int*)d_in[1];
  const int*   xlen  = (const int*)d_in[2];
  const int*   decx  = (const int*)d_in[3];
  const float* emb   = (const float*)d_in[4];
  const float* Wenc  = (const float*)d_in[5];
  const float* Uenc  = (const float*)d_in[6];
  const float* benc  = (const float*)d_in[7];
  const float* We2d  = (const float*)d_in[8];
  const float* be2d  = (const float*)d_in[9];
  const float* Wdec  = (const float*)d_in[10];
  const float* Udec  = (const float*)d_in[11];
  const float* bdec  = (const float*)d_in[12];
  const float* Wattn = (const float*)d_in[13];
  const float* Wout  = (const float*)d_in[14];
  const float* bout  = (const float*)d_in[15];
  const float* Wgen  = (const float*)d_in[16];
  const float* Wcopy = (const float*)d_in[17];
  const float* bcopy = (const float*)d_in[18];
  float* out = (float*)d_out;
  float* ws  = (float*)d_ws;

  // ---- workspace layout (float offsets), ~47.6 MB ----
  float*    Xenc   = ws + 0;                         // 8,388,608 fl (dead after encoder)
  ushort_t* WgenT  = (ushort_t*)(ws + 0);            // phase2: 12.8M ush (decoder dispatch)
  ushort_t* cp_bf  = (ushort_t*)(ws + 6400000);      // phase2: 2.1M ush
  float*    dqb    = ws + 8388608;
  float*    ctxb   = ws + 8519680;
  float*    attno  = ws + 8650752;
  float*    cseq   = ws + 8781824;
  float*    rsum   = ws + 8912896;                   // 512
  float*    rowlog = ws + 8913408;                   // 512
  ushort_t* Abf    = (ushort_t*)(ws + 8913920);
  ushort_t* catb   = (ushort_t*)(ws + 8979456);
  ushort_t* decObf = (ushort_t*)(ws + 9110528);
  ushort_t* xembbf = (ushort_t*)(ws + 9176064);
  ushort_t* dembbf = (ushort_t*)(ws + 9700352);
  float*    Xdec   = ws + 9733120;
  ushort_t* WencT  = (ushort_t*)(ws + 10257408);
  ushort_t* WdecT  = (ushort_t*)(ws + 10322944);
  ushort_t* We2dT  = (ushort_t*)(ws + 10388480);
  ushort_t* WattnT = (ushort_t*)(ws + 10421248);
  ushort_t* WoutT  = (ushort_t*)(ws + 10454016);
  ushort_t* WcopyT = (ushort_t*)(ws + 10519552);
  unsigned* Upk2E  = (unsigned*)(ws + 10552320);
  unsigned* Upk2D  = (unsigned*)(ws + 10683392);
  ushort_t* encObf = (ushort_t*)(ws + 10814464);
  float*    ehc    = ws + 11863040;
  ushort_t* ehcbf  = (ushort_t*)(ws + 11879424);
  float*    h0c0   = ws + 11887616;

  float* sh  = out + (size_t)B_ * T_ * VO_;
  float* scf = sh + B_ * HD_;

  hipMemsetAsync(rsum, 0, 512 * sizeof(float), stream);

  hipLaunchKernelGGL(prep_kernel, dim3(5952), dim3(256), 0, stream,
                     Wenc, Wdec, We2d, Wattn, Wout, Wcopy, Uenc, Udec, x, decx, emb,
                     WencT, WdecT, We2dT, WattnT, WoutT, WcopyT, Upk2E, Upk2D,
                     xembbf, dembbf);

  hipLaunchKernelGGL(mfma_gemm, dim3(16, 128), dim3(256), 0, stream,
                     xembbf, WencT, benc, Xenc, (ushort_t*)nullptr, (float*)nullptr,
                     B_ * S_, 1024, 128, 1024, 0);
  hipLaunchKernelGGL(mfma_gemm, dim3(16, 8), dim3(256), 0, stream,
                     dembbf, WdecT, bdec, Xdec, (ushort_t*)nullptr, (float*)nullptr,
                     B_ * T_, 1024, 128, 1024, 0);

  hipLaunchKernelGGL(lstm4, dim3(32), dim3(1024), 0, stream,
                     Xenc, Upk2E, (const float*)nullptr, (const float*)nullptr,
                     encObf, ehc, ehc + 32 * 256, S_,
                     (const float*)nullptr, (ushort_t*)nullptr);

  hipLaunchKernelGGL(f2bf_kernel, dim3(64), dim3(256), 0, stream, ehc, ehcbf, 64 * 256);
  hipLaunchKernelGGL(mfma_gemm, dim3(4, 1), dim3(256), 0, stream,
                     ehcbf, We2dT, be2d, h0c0, (ushort_t*)nullptr, (float*)nullptr,
                     64, 256, 256, 256, 0);

  // decoder + fused Wgen transpose on the idle 224 CUs (Xenc region is dead now)
  hipLaunchKernelGGL(lstm4, dim3(32 + 3128), dim3(1024), 0, stream,
                     Xdec, Upk2D, h0c0, h0c0 + 32 * 256, decObf, sh, scf, T_,
                     Wgen, WgenT);

  hipLaunchKernelGGL(mfma_gemm, dim3(4, 8), dim3(256), 0, stream,
                     decObf, WattnT, (const float*)nullptr, dqb, (ushort_t*)nullptr,
                     (float*)nullptr, B_ * T_, 256, 256, 256, 0);
  hipLaunchKernelGGL(attn_kernel, dim3(B_ * T_), dim3(256), 0, stream, dqb, encObf, xlen, ctxb);
  hipLaunchKernelGGL(concat_bf, dim3(1024), dim3(256), 0, stream, ctxb, decObf, catb);
  hipLaunchKernelGGL(mfma_gemm, dim3(4, 8), dim3(256), 0, stream,
                     catb, WoutT, bout, attno, (ushort_t*)nullptr, (float*)nullptr,
                     B_ * T_, 256, 512, 256, 1);
  hipLaunchKernelGGL(f2bf_kernel, dim3(512), dim3(256), 0, stream, attno, Abf, B_ * T_ * 256);
  hipLaunchKernelGGL(mfma_gemm, dim3(4, 128), dim3(256), 0, stream,
                     encObf, WcopyT, bcopy, (float*)nullptr, cp_bf, (float*)nullptr,
                     B_ * S_, 256, 256, 256, 1);
  hipLaunchKernelGGL(mfma_gemm, dim3(782, 8), dim3(256), 0, stream,
                     Abf, WgenT, (const float*)nullptr, out, (ushort_t*)nullptr, rsum,
                     B_ * T_, V_, 256, VO_, 2);
  hipLaunchKernelGGL(pad_kernel, dim3(200), dim3(256), 0, stream, out);
  hipLaunchKernelGGL(copyseq_kernel, dim3(B_ * T_), dim3(256), 0, stream, attno, cp_bf, xlen, cseq);
  hipLaunchKernelGGL(scatter_kernel, dim3(512), dim3(256), 0, stream, cseq, xoov, out, rsum);
  hipLaunchKernelGGL(rowlog_kernel, dim3(2), dim3(256), 0, stream, rsum, rowlog);
  hipLaunchKernelGGL(finalize_kernel, dim3((B_ * T_ * VO_ + 255) / 256), dim3(256), 0, stream,
                     out, rowlog);
}